// Round 3
// baseline (583.610 us; speedup 1.0000x reference)
//
#include <hip/hip_runtime.h>
#include <hip/hip_bf16.h>

#define CIN   512
#define COUT  512
#define HW    4096
#define PADW  66
#define NB    16

static constexpr float LIN_SCALE = 0.044194173824159216f;  // 1/sqrt(512)
static constexpr float W_SCALE   = 0.014731391274719738f;  // 1/sqrt(512*9)

typedef __attribute__((ext_vector_type(8))) short bf16x8;
typedef __attribute__((ext_vector_type(4))) float f32x4;

__device__ __forceinline__ unsigned short f2us(float f) {
    __hip_bfloat16 h = __float2bfloat16(f); unsigned short u; __builtin_memcpy(&u, &h, 2); return u;
}

typedef const __attribute__((address_space(1))) unsigned int guint;
typedef __attribute__((address_space(3))) unsigned int luint;
__device__ __forceinline__ void gload_lds16(const void* g, void* l) {
    __builtin_amdgcn_global_load_lds((guint*)g, (luint*)l, 16, 0, 0);
}

// ---------------- s[n][i] = lin_scale * style[n] . style_w[i] + style_b[i] ----------------
__global__ void k_style(const float* __restrict__ style,
                        const float* __restrict__ style_w,
                        const float* __restrict__ style_b,
                        float* __restrict__ s) {
    int wid  = (blockIdx.x * blockDim.x + threadIdx.x) >> 6;
    int lane = threadIdx.x & 63;
    int n = wid >> 9, i = wid & 511;
    float sum = 0.f;
    for (int j = lane; j < 512; j += 64)
        sum += style[n * 512 + j] * style_w[i * 512 + j];
    for (int m = 32; m; m >>= 1) sum += __shfl_xor(sum, m, 64);
    if (lane == 0) s[n * 512 + i] = sum * LIN_SCALE + style_b[i];
}

// ---------------- wsq[o][i] = sum_tap (w*wscale)^2 ; wt[tap][o][i] = bf16(w*wscale) -------
__global__ void k_wprep(const float* __restrict__ weight,
                        float* __restrict__ wsq,
                        __hip_bfloat16* __restrict__ wt) {
    int oi = blockIdx.x * 256 + threadIdx.x;   // 0..262143  (= o*512 + i)
    float sq = 0.f;
#pragma unroll
    for (int tp = 0; tp < 9; ++tp) {
        float v = weight[(size_t)oi * 9 + tp] * W_SCALE;
        sq += v * v;
        wt[(size_t)tp * (COUT * CIN) + oi] = __float2bfloat16(v);
    }
    wsq[oi] = sq;
}

// ---------------- demod[n][o] = rsqrt(sum_i wsq[o][i]*s[n][i]^2 + eps) --------------------
__global__ void k_demod(const float* __restrict__ wsq, const float* __restrict__ s,
                        float* __restrict__ demod) {
    int wid  = (blockIdx.x * blockDim.x + threadIdx.x) >> 6;
    int lane = threadIdx.x & 63;
    int n = wid >> 9, o = wid & 511;
    float sum = 0.f;
    for (int i = lane; i < 512; i += 64) {
        float sv = s[n * 512 + i];
        sum += wsq[o * 512 + i] * sv * sv;
    }
    for (int m = 32; m; m >>= 1) sum += __shfl_xor(sum, m, 64);
    if (lane == 0) demod[n * 512 + o] = rsqrtf(sum + 1e-8f);
}

// ---------------- zero the pad border of xs_t [16][66][66][512] ---------------------------
__global__ void k_border(__hip_bfloat16* __restrict__ xs) {
    int bp = blockIdx.x, n = blockIdx.y, t = threadIdx.x;  // 260 border pixels, 64 threads
    int hp, wp;
    if (bp < 66)       { hp = 0;  wp = bp; }
    else if (bp < 132) { hp = 65; wp = bp - 66; }
    else { int k2 = bp - 132; hp = 1 + (k2 >> 1); wp = (k2 & 1) ? 65 : 0; }
    uint4 z = make_uint4(0u, 0u, 0u, 0u);
    *(uint4*)(xs + (((size_t)n * PADW * PADW) + hp * PADW + wp) * 512 + t * 8) = z;
}

// ---- xs_t[n][h+1][w+1][i] = bf16(x[n][i][h][w] * s[n][i])  (f32 NCHW -> padded bf16 NHWC)
__global__ void k_xs(const float* __restrict__ x, const float* __restrict__ s,
                     __hip_bfloat16* __restrict__ xs) {
    const int h = blockIdx.x;   // 0..63
    const int n = blockIdx.y;   // 0..15
    const int t = threadIdx.x;  // 0..255
    const int PITCH = 66;       // f32 elements; stride 66 mod 32 = 2 banks
    __shared__ float lds[64 * 66];   // 16.9 KB: 64 i-rows x 64 w
    for (int ic = 0; ic < 8; ++ic) {
        const int i0 = ic * 64;
        __syncthreads();
        // load 64 i-rows x 64 w, float4 (coalesced 16B along w)
#pragma unroll
        for (int j = 0; j < 4; ++j) {
            int idx = j * 256 + t;          // 0..1023
            int il = idx >> 4;              // 0..63
            int wq = (idx & 15) * 4;        // 0..60
            float4 v = *(const float4*)(x + (((size_t)n * 512 + i0 + il) * HW) + h * 64 + wq);
            float* dst = &lds[il * PITCH + wq];
            dst[0] = v.x; dst[1] = v.y; dst[2] = v.z; dst[3] = v.w;
        }
        __syncthreads();
        // write transposed (16B = 8 bf16 along i) with s multiply
#pragma unroll
        for (int j = 0; j < 2; ++j) {
            int idx = j * 256 + t;          // 0..511
            int wp = idx >> 3;              // 0..63
            int ib = (idx & 7) * 8;         // 0..56
            unsigned short tmp[8];
#pragma unroll
            for (int r = 0; r < 8; ++r) {
                float xv = lds[(ib + r) * PITCH + wp];
                float sv = s[n * 512 + i0 + ib + r];
                tmp[r] = f2us(xv * sv);
            }
            uint4 o;
            o.x = (unsigned)tmp[0] | ((unsigned)tmp[1] << 16);
            o.y = (unsigned)tmp[2] | ((unsigned)tmp[3] << 16);
            o.z = (unsigned)tmp[4] | ((unsigned)tmp[5] << 16);
            o.w = (unsigned)tmp[6] | ((unsigned)tmp[7] << 16);
            *(uint4*)(xs + ((size_t)((n * PADW + h + 1) * PADW + (wp + 1))) * 512 + i0 + ib) = o;
        }
    }
}

// ---------------- main conv: per-sample implicit GEMM, 128x128 tile, BK=64 ----------------
// C[o][hw] = sum_{tap,i} wt[tap][o][i] * xs[n][h+kh][w+kw][i], scaled by demod[n][o]
__global__ __launch_bounds__(256) void k_conv(
        const __hip_bfloat16* __restrict__ wt,     // [9][512][512]
        const __hip_bfloat16* __restrict__ xs,     // [16][66][66][512]
        const float* __restrict__ demod,           // [16][512]
        float* __restrict__ out) {                 // [16][512][64][64] f32
    __shared__ char lds[32768];                    // A: 0..16K (128x64 bf16), B: 16K..32K
    const int tid = threadIdx.x;
    const int wave = tid >> 6, lane = tid & 63;
    const int tN = blockIdx.x;     // hw tile 0..31
    const int o0 = blockIdx.y * 128;
    const int n  = blockIdx.z;

    // staging: each wave stages 32 rows (4KB) of A and of B per K-chunk,
    // as 4 x global_load_lds_dwordx4 (each stages 8 rows = 1KB: lane -> base+lane*16).
    const int cb = (lane & 7) * 8;                 // i-offset within BK=64 (16B chunk)
    size_t Aoff[4], Boff[4];
#pragma unroll
    for (int j = 0; j < 4; ++j) {
        const int r = wave * 32 + j * 8 + (lane >> 3);   // row in 128-tile
        Aoff[j] = (size_t)(o0 + r) * CIN + cb;
        const int hw0 = tN * 128 + r;
        Boff[j] = ((size_t)(hw0 >> 6) * PADW + (hw0 & 63)) * CIN + cb;  // tap adds (kh*66+kw)*512
    }
    const __hip_bfloat16* xsn = xs + (size_t)n * PADW * PADW * CIN;

    char* ldsA = lds + wave * 4096;
    char* ldsB = lds + 16384 + wave * 4096;

    // fragment read pointers: A row = o (m), B row = pixel (n), 8 bf16 along k per lane
    const int qd = lane >> 4, col = lane & 15;
    const char* aRd = lds + (((wave & 1) * 64 + col) * 128) + qd * 16;
    const char* bRd = lds + 16384 + (((wave >> 1) * 64 + col) * 128) + qd * 16;

    f32x4 acc[4][4] = {};

    for (int tp = 0; tp < 9; ++tp) {
        const size_t tapA = (size_t)tp * (COUT * CIN);
        const int kh = tp / 3, kw = tp % 3;
        const size_t tapB = ((size_t)kh * PADW + kw) * CIN;
        for (int c = 0; c < 8; ++c) {
            __syncthreads();
#pragma unroll
            for (int j = 0; j < 4; ++j) {
                gload_lds16(wt  + tapA + Aoff[j] + c * 64, ldsA + j * 1024);
                gload_lds16(xsn + tapB + Boff[j] + c * 64, ldsB + j * 1024);
            }
            __syncthreads();
#pragma unroll
            for (int kk = 0; kk < 2; ++kk) {
                bf16x8 af[4], bfr[4];
#pragma unroll
                for (int mt = 0; mt < 4; ++mt)
                    af[mt] = *(const bf16x8*)(aRd + mt * 16 * 128 + kk * 64);
#pragma unroll
                for (int nt = 0; nt < 4; ++nt)
                    bfr[nt] = *(const bf16x8*)(bRd + nt * 16 * 128 + kk * 64);
#pragma unroll
                for (int mt = 0; mt < 4; ++mt)
#pragma unroll
                    for (int nt = 0; nt < 4; ++nt)
                        acc[mt][nt] = __builtin_amdgcn_mfma_f32_16x16x32_bf16(
                            af[mt], bfr[nt], acc[mt][nt], 0, 0, 0);
            }
        }
    }

    // epilogue: C[row=qd*4+reg][col=lane&15], scale by demod, store f32 NCHW
    const int oBase  = o0 + (wave & 1) * 64;
    const int hwBase = tN * 128 + (wave >> 1) * 64 + col;
#pragma unroll
    for (int mt = 0; mt < 4; ++mt) {
#pragma unroll
        for (int rg = 0; rg < 4; ++rg) {
            const int o = oBase + mt * 16 + qd * 4 + rg;
            const float dm = demod[n * 512 + o];
            float* orow = out + ((size_t)(n * COUT + o)) * HW + hwBase;
#pragma unroll
            for (int nt = 0; nt < 4; ++nt)
                orow[nt * 16] = acc[mt][nt][rg] * dm;
        }
    }
}

extern "C" void kernel_launch(void* const* d_in, const int* in_sizes, int n_in,
                              void* d_out, int out_size, void* d_ws, size_t ws_size,
                              hipStream_t stream) {
    const float* x       = (const float*)d_in[0];
    const float* style   = (const float*)d_in[1];
    const float* weight  = (const float*)d_in[2];
    const float* style_w = (const float*)d_in[3];
    const float* style_b = (const float*)d_in[4];
    float* out = (float*)d_out;

    char* ws = (char*)d_ws;
    // ws layout (bytes): s 0..32K | wsq 32K..1.03M | demod .. | wt 9*512*512*2 | xs_t 71.3M
    float*          s_buf  = (float*)(ws + 0);
    float*          wsq    = (float*)(ws + 32768);
    float*          demod  = (float*)(ws + 1081344);
    __hip_bfloat16* wt     = (__hip_bfloat16*)(ws + 1114112);
    __hip_bfloat16* xs     = (__hip_bfloat16*)(ws + 5832704);
    // total = 77,201,408 bytes

    k_style <<<dim3(2048),     dim3(256), 0, stream>>>(style, style_w, style_b, s_buf);
    k_wprep <<<dim3(1024),     dim3(256), 0, stream>>>(weight, wsq, wt);
    k_demod <<<dim3(2048),     dim3(256), 0, stream>>>(wsq, s_buf, demod);
    k_border<<<dim3(260, 16),  dim3(64),  0, stream>>>(xs);
    k_xs    <<<dim3(64, 16),   dim3(256), 0, stream>>>(x, s_buf, xs);
    k_conv  <<<dim3(32, 4, 16), dim3(256), 0, stream>>>(wt, xs, demod, out);
}